// Round 2
// baseline (311.011 us; speedup 1.0000x reference)
//
#include <hip/hip_runtime.h>

typedef __attribute__((ext_vector_type(8))) short short8;
typedef __attribute__((ext_vector_type(4))) float f32x4;
typedef unsigned short u16;
typedef unsigned int   u32;

#define S_  2048
#define D_  1024
#define H_  16
#define DH_ 64
#define M_  4096     // B*S
#define K_  1024
#define N3_ 3072

// round-to-nearest-even fp32 -> bf16
__device__ __forceinline__ u16 f2bf(float f) {
    u32 u = __float_as_uint(f);
    u32 r = u + 0x7FFFu + ((u >> 16) & 1u);
    return (u16)(r >> 16);
}

// async global->LDS, 16B per lane. LDS dest must be the wave-uniform base
// (lane i lands at base + i*16); global src is per-lane.
__device__ __forceinline__ void gload_lds16(const void* g, void* l) {
    __builtin_amdgcn_global_load_lds(
        (const __attribute__((address_space(1))) u32*)g,
        (__attribute__((address_space(3))) u32*)l, 16, 0, 0);
}

// ---------------------------------------------------------------------------
// prep: fp32 -> bf16 straight convert (x)
// ---------------------------------------------------------------------------
__global__ __launch_bounds__(256) void convert_f32_bf16(
    const float* __restrict__ in, u16* __restrict__ out, int n4)
{
    int i = blockIdx.x * 256 + threadIdx.x;
    const int stride = gridDim.x * 256;
    for (; i < n4; i += stride) {
        float4 v = ((const float4*)in)[i];
        ushort4 o;
        o.x = f2bf(v.x); o.y = f2bf(v.y); o.z = f2bf(v.z); o.w = f2bf(v.w);
        ((ushort4*)out)[i] = o;
    }
}

// ---------------------------------------------------------------------------
// prep: transpose + convert.  in [rows][cols] f32  ->  out [cols][rows] bf16
// ---------------------------------------------------------------------------
__global__ __launch_bounds__(256) void transpose_f32_bf16(
    const float* __restrict__ in, u16* __restrict__ out, int rows, int cols)
{
    __shared__ float tile[32][33];
    const int tx = threadIdx.x & 31;
    const int ty = threadIdx.x >> 5;          // 0..7
    #pragma unroll
    for (int i = 0; i < 4; ++i) {
        int r = blockIdx.y * 32 + ty + i * 8;
        int c = blockIdx.x * 32 + tx;
        tile[ty + i * 8][tx] = in[(size_t)r * cols + c];
    }
    __syncthreads();
    #pragma unroll
    for (int i = 0; i < 4; ++i) {
        int orow = blockIdx.x * 32 + ty + i * 8;   // out row  (= in col)
        int ocol = blockIdx.y * 32 + tx;           // out col  (= in row)
        out[(size_t)orow * rows + ocol] = f2bf(tile[tx][ty + i * 8]);
    }
}

// ---------------------------------------------------------------------------
// bf16 MFMA GEMM, m97 structure: 128x128 tile, BK=32, 4 waves, per wave a
// 64x64 sub-tile = 4x4 fragments of 16x16x32.  A [M][K] bf16, Bt [N][K] bf16.
// EPI 0: QKV epilogue (bias fp32, q scaled 0.125, scatter head-major bf16).
// EPI 1: proj epilogue (bias fp32, fp32 row-major out).
// ---------------------------------------------------------------------------
template <int EPI>
__global__ __launch_bounds__(256) void mfma_gemm(
    const u16* __restrict__ A, const u16* __restrict__ Bt,
    const float* __restrict__ bias,
    u16* __restrict__ qd, u16* __restrict__ kd, u16* __restrict__ vd,
    float* __restrict__ outp)
{
    __shared__ u16 As[128 * 32];   // [row][k] linear, 64B rows
    __shared__ u16 Bs[128 * 32];   // [outcol][k] linear

    const int t  = threadIdx.x;
    const int wv = t >> 6;                  // wave 0..3
    const int ln = t & 63;
    const int wr = wv >> 1, wc = wv & 1;    // 2x2 wave grid
    const int r0 = blockIdx.y * 128;
    const int c0 = blockIdx.x * 128;
    const int li = ln & 15, lq = ln >> 4;

    f32x4 acc[4][4];
    #pragma unroll
    for (int m = 0; m < 4; ++m)
        #pragma unroll
        for (int n = 0; n < 4; ++n) acc[m][n] = (f32x4){0.f, 0.f, 0.f, 0.f};

    for (int k0 = 0; k0 < K_; k0 += 32) {
        __syncthreads();                    // prior frag reads done
        #pragma unroll
        for (int qq = 0; qq < 2; ++qq) {
            const int slot = wv * 128 + qq * 64 + ln;      // 16B slots, 512 total
            const int row  = slot >> 2;
            const int col  = (slot & 3) * 8;
            gload_lds16(A  + (size_t)(r0 + row) * K_ + k0 + col,
                        &As[(size_t)(wv * 128 + qq * 64) * 8]);
            gload_lds16(Bt + (size_t)(c0 + row) * K_ + k0 + col,
                        &Bs[(size_t)(wv * 128 + qq * 64) * 8]);
        }
        __syncthreads();                    // vmcnt drained by compiler

        short8 af[4], bfr[4];
        const int qk = lq * 8;
        #pragma unroll
        for (int m = 0; m < 4; ++m)
            af[m] = *(const short8*)&As[(wr * 64 + m * 16 + li) * 32 + qk];
        #pragma unroll
        for (int n = 0; n < 4; ++n)
            bfr[n] = *(const short8*)&Bs[(wc * 64 + n * 16 + li) * 32 + qk];
        #pragma unroll
        for (int m = 0; m < 4; ++m)
            #pragma unroll
            for (int n = 0; n < 4; ++n)
                acc[m][n] = __builtin_amdgcn_mfma_f32_16x16x32_bf16(
                    af[m], bfr[n], acc[m][n], 0, 0, 0);
    }

    // C/D layout: col = lane&15, row = (lane>>4)*4 + reg
    if (EPI == 0) {
        #pragma unroll
        for (int n = 0; n < 4; ++n) {
            const int gcol  = c0 + wc * 64 + n * 16 + li;   // 0..3071
            const int which = gcol >> 10;                    // uniform per frag
            const int rem   = gcol & 1023;
            const int h     = rem >> 6;
            const int dh    = rem & 63;
            u16* dst = (which == 0) ? qd : (which == 1) ? kd : vd;
            const float scl = (which == 0) ? 0.125f : 1.0f;
            const float bb  = bias[gcol];
            #pragma unroll
            for (int m = 0; m < 4; ++m)
                #pragma unroll
                for (int r = 0; r < 4; ++r) {
                    const int grow = r0 + wr * 64 + m * 16 + lq * 4 + r;
                    const int b = grow >> 11, s = grow & (S_ - 1);
                    dst[((size_t)(b * H_ + h) * S_ + s) * DH_ + dh] =
                        f2bf((acc[m][n][r] + bb) * scl);
                }
        }
    } else {
        #pragma unroll
        for (int n = 0; n < 4; ++n) {
            const int gcol = c0 + wc * 64 + n * 16 + li;
            const float bb = bias[gcol];
            #pragma unroll
            for (int m = 0; m < 4; ++m)
                #pragma unroll
                for (int r = 0; r < 4; ++r) {
                    const int grow = r0 + wr * 64 + m * 16 + lq * 4 + r;
                    outp[(size_t)grow * D_ + gcol] = acc[m][n][r] + bb;
                }
        }
    }
}

// ---------------------------------------------------------------------------
// flash attention, bf16 MFMA. block = 4 waves, one (b,h) x 64-query tile.
// wave wv owns Q rows 16*wv..16*wv+15 of the tile (QK^T strip, softmax, PV).
// LDS tiles padded to 72 (stride 144B) -> bank-balanced b128 frag reads.
// ---------------------------------------------------------------------------
__global__ __launch_bounds__(256) void attn_mfma(
    const u16* __restrict__ qws, const u16* __restrict__ kws,
    const u16* __restrict__ vws, u16* __restrict__ ao)
{
    __shared__ u16 Qs[64][72];
    __shared__ u16 Ks[64][72];   // [kv][d]
    __shared__ u16 Vt[64][72];   // [d][kv]  (transposed)
    __shared__ u16 Ps[64][72];   // [qrow][kv], wave-private strips

    const int t  = threadIdx.x;
    const int wv = t >> 6, ln = t & 63;
    const int li = ln & 15, lq = ln >> 4;
    const int bh = blockIdx.y;
    const int q0 = blockIdx.x * 64;

    const u16* Qp = qws + (size_t)bh * S_ * DH_;
    const u16* Kp = kws + (size_t)bh * S_ * DH_;
    const u16* Vp = vws + (size_t)bh * S_ * DH_;

    #pragma unroll
    for (int i = 0; i < 2; ++i) {
        const int s = t + i * 256;           // 512 segs of 8 elems
        const int row = s >> 3, c8 = (s & 7) * 8;
        *(short8*)&Qs[row][c8] = *(const short8*)(Qp + (size_t)(q0 + row) * DH_ + c8);
    }

    f32x4 o[4];
    #pragma unroll
    for (int n = 0; n < 4; ++n) o[n] = (f32x4){0.f, 0.f, 0.f, 0.f};
    float mrow[4] = {-3e38f, -3e38f, -3e38f, -3e38f};
    float lrow[4] = {0.f, 0.f, 0.f, 0.f};

    for (int kt = 0; kt < S_ / 64; ++kt) {
        const int k0 = kt * 64;
        __syncthreads();                     // prior K/V reads done (covers Qs store order too)
        #pragma unroll
        for (int i = 0; i < 2; ++i) {
            const int s = t + i * 256;
            const int row = s >> 3, c8 = (s & 7) * 8;
            *(short8*)&Ks[row][c8] = *(const short8*)(Kp + (size_t)(k0 + row) * DH_ + c8);
            short8 vv = *(const short8*)(Vp + (size_t)(k0 + row) * DH_ + c8);
            #pragma unroll
            for (int j = 0; j < 8; ++j) Vt[c8 + j][row] = vv[j];
        }
        __syncthreads();

        // S = Q K^T  (wave strip: 16 rows x 64 cols)
        f32x4 sacc[4];
        #pragma unroll
        for (int j = 0; j < 4; ++j) sacc[j] = (f32x4){0.f, 0.f, 0.f, 0.f};
        #pragma unroll
        for (int ks = 0; ks < 2; ++ks) {
            short8 aq = *(const short8*)&Qs[wv * 16 + li][ks * 32 + lq * 8];
            #pragma unroll
            for (int j = 0; j < 4; ++j) {
                short8 bk = *(const short8*)&Ks[j * 16 + li][ks * 32 + lq * 8];
                sacc[j] = __builtin_amdgcn_mfma_f32_16x16x32_bf16(aq, bk, sacc[j], 0, 0, 0);
            }
        }

        // online softmax (rows: lq*4+r within strip; cols j*16+li)
        #pragma unroll
        for (int r = 0; r < 4; ++r) {
            float mx = fmaxf(fmaxf(sacc[0][r], sacc[1][r]), fmaxf(sacc[2][r], sacc[3][r]));
            mx = fmaxf(mx, __shfl_xor(mx, 1));
            mx = fmaxf(mx, __shfl_xor(mx, 2));
            mx = fmaxf(mx, __shfl_xor(mx, 4));
            mx = fmaxf(mx, __shfl_xor(mx, 8));
            const float mnew = fmaxf(mrow[r], mx);
            const float p0 = __expf(sacc[0][r] - mnew);
            const float p1 = __expf(sacc[1][r] - mnew);
            const float p2 = __expf(sacc[2][r] - mnew);
            const float p3 = __expf(sacc[3][r] - mnew);
            float rs = p0 + p1 + p2 + p3;
            rs += __shfl_xor(rs, 1);
            rs += __shfl_xor(rs, 2);
            rs += __shfl_xor(rs, 4);
            rs += __shfl_xor(rs, 8);
            const float scl = __expf(mrow[r] - mnew);
            lrow[r] = lrow[r] * scl + rs;
            mrow[r] = mnew;
            const int prow = wv * 16 + lq * 4 + r;
            Ps[prow][ 0 + li] = f2bf(p0);
            Ps[prow][16 + li] = f2bf(p1);
            Ps[prow][32 + li] = f2bf(p2);
            Ps[prow][48 + li] = f2bf(p3);
            #pragma unroll
            for (int n = 0; n < 4; ++n) o[n][r] *= scl;
        }

        // O += P V   (P strip is wave-private: no barrier, lgkmcnt only)
        #pragma unroll
        for (int ks = 0; ks < 2; ++ks) {
            short8 ap = *(const short8*)&Ps[wv * 16 + li][ks * 32 + lq * 8];
            #pragma unroll
            for (int n = 0; n < 4; ++n) {
                short8 bv = *(const short8*)&Vt[n * 16 + li][ks * 32 + lq * 8];
                o[n] = __builtin_amdgcn_mfma_f32_16x16x32_bf16(ap, bv, o[n], 0, 0, 0);
            }
        }
    }

    // normalize + write merged-head bf16 [B*S][D]
    const int b = bh >> 4, h = bh & 15;
    #pragma unroll
    for (int r = 0; r < 4; ++r) {
        const float inv = 1.0f / lrow[r];
        const int s = q0 + wv * 16 + lq * 4 + r;
        #pragma unroll
        for (int n = 0; n < 4; ++n) {
            const int col = h * 64 + n * 16 + li;
            ao[((size_t)b * S_ + s) * D_ + col] = f2bf(o[n][r] * inv);
        }
    }
}

// ---------------------------------------------------------------------------
extern "C" void kernel_launch(void* const* d_in, const int* in_sizes, int n_in,
                              void* d_out, int out_size, void* d_ws, size_t ws_size,
                              hipStream_t stream)
{
    const float* x      = (const float*)d_in[0];
    const float* w_attn = (const float*)d_in[1];
    const float* b_attn = (const float*)d_in[2];
    const float* w_proj = (const float*)d_in[3];
    const float* b_proj = (const float*)d_in[4];
    float* out = (float*)d_out;

    char* ws = (char*)d_ws;
    u16* x_bf = (u16*)(ws);                              //  8 MB  [4096][1024]
    u16* wat  = (u16*)(ws + 8388608);                    //  6 MB  [3072][1024] (W_attn^T)
    u16* wpj  = (u16*)(ws + 14680064);                   //  2 MB  [1024][1024] (W_proj^T)
    u16* qws  = (u16*)(ws + 16777216);                   //  8 MB  [32][2048][64] (pre-scaled)
    u16* kws  = (u16*)(ws + 25165824);                   //  8 MB
    u16* vws  = (u16*)(ws + 33554432);                   //  8 MB
    u16* ao   = (u16*)(ws + 41943040);                   //  8 MB  [4096][1024]
    // total 48 MB

    convert_f32_bf16<<<1024, 256, 0, stream>>>(x, x_bf, M_ * K_ / 4);
    transpose_f32_bf16<<<dim3(N3_ / 32, K_ / 32), 256, 0, stream>>>(w_attn, wat, K_, N3_);
    transpose_f32_bf16<<<dim3(D_ / 32, K_ / 32), 256, 0, stream>>>(w_proj, wpj, K_, D_);

    mfma_gemm<0><<<dim3(N3_ / 128, M_ / 128), 256, 0, stream>>>(
        x_bf, wat, b_attn, qws, kws, vws, nullptr);

    attn_mfma<<<dim3(S_ / 64, 32), 256, 0, stream>>>(qws, kws, vws, ao);

    mfma_gemm<1><<<dim3(D_ / 128, M_ / 128), 256, 0, stream>>>(
        ao, wpj, b_proj, nullptr, nullptr, nullptr, out);
}

// Round 5
// 253.357 us; speedup vs baseline: 1.2276x; 1.2276x over previous
//
#include <hip/hip_runtime.h>

typedef __attribute__((ext_vector_type(8))) short short8;
typedef __attribute__((ext_vector_type(4))) float f32x4;
typedef unsigned short u16;
typedef unsigned int   u32;

#define S_  2048
#define D_  1024
#define H_  16
#define DH_ 64
#define M_  4096     // B*S
#define K_  1024
#define N3_ 3072

// round-to-nearest-even fp32 -> bf16
__device__ __forceinline__ u16 f2bf(float f) {
    u32 u = __float_as_uint(f);
    u32 r = u + 0x7FFFu + ((u >> 16) & 1u);
    return (u16)(r >> 16);
}

// async global->LDS, 16B per lane (wave-uniform LDS base, per-lane global src)
__device__ __forceinline__ void gload_lds16(const void* g, void* l) {
    __builtin_amdgcn_global_load_lds(
        (const __attribute__((address_space(1))) u32*)g,
        (__attribute__((address_space(3))) u32*)l, 16, 0, 0);
}

// ---------------------------------------------------------------------------
// prep: fp32 -> bf16 straight convert (x)
// ---------------------------------------------------------------------------
__global__ __launch_bounds__(256) void convert_f32_bf16(
    const float* __restrict__ in, u16* __restrict__ out, int n4)
{
    int i = blockIdx.x * 256 + threadIdx.x;
    const int stride = gridDim.x * 256;
    for (; i < n4; i += stride) {
        float4 v = ((const float4*)in)[i];
        ushort4 o;
        o.x = f2bf(v.x); o.y = f2bf(v.y); o.z = f2bf(v.z); o.w = f2bf(v.w);
        ((ushort4*)out)[i] = o;
    }
}

// ---------------------------------------------------------------------------
// prep: transpose + convert.  in [rows][cols] f32  ->  out [cols][rows] bf16
// ---------------------------------------------------------------------------
__global__ __launch_bounds__(256) void transpose_f32_bf16(
    const float* __restrict__ in, u16* __restrict__ out, int rows, int cols)
{
    __shared__ float tile[32][33];
    const int tx = threadIdx.x & 31;
    const int ty = threadIdx.x >> 5;          // 0..7
    #pragma unroll
    for (int i = 0; i < 4; ++i) {
        int r = blockIdx.y * 32 + ty + i * 8;
        int c = blockIdx.x * 32 + tx;
        tile[ty + i * 8][tx] = in[(size_t)r * cols + c];
    }
    __syncthreads();
    #pragma unroll
    for (int i = 0; i < 4; ++i) {
        int orow = blockIdx.x * 32 + ty + i * 8;   // out row  (= in col)
        int ocol = blockIdx.y * 32 + tx;           // out col  (= in row)
        out[(size_t)orow * rows + ocol] = f2bf(tile[tx][ty + i * 8]);
    }
}

// ---------------------------------------------------------------------------
// bf16 MFMA GEMM, m97 structure: 128x128 tile, BK=32, 4 waves.
// EPI 0: QKV epilogue -> q (x0.125) [bh][s][dh], k [bh][s][dh], v TRANSPOSED
//        [bh][dh][s].   EPI 1: proj epilogue, fp32 out + bias.
// ---------------------------------------------------------------------------
template <int EPI>
__global__ __launch_bounds__(256) void mfma_gemm(
    const u16* __restrict__ A, const u16* __restrict__ Bt,
    const float* __restrict__ bias,
    u16* __restrict__ qd, u16* __restrict__ kd, u16* __restrict__ vd,
    float* __restrict__ outp)
{
    __shared__ u16 As[128 * 32];   // [row][k] linear, 64B rows
    __shared__ u16 Bs[128 * 32];   // [outcol][k] linear

    const int t  = threadIdx.x;
    const int wv = t >> 6;                  // wave 0..3
    const int ln = t & 63;
    const int wr = wv >> 1, wc = wv & 1;    // 2x2 wave grid
    const int r0 = blockIdx.y * 128;
    const int c0 = blockIdx.x * 128;
    const int li = ln & 15, lq = ln >> 4;

    f32x4 acc[4][4];
    #pragma unroll
    for (int m = 0; m < 4; ++m)
        #pragma unroll
        for (int n = 0; n < 4; ++n) acc[m][n] = (f32x4){0.f, 0.f, 0.f, 0.f};

    for (int k0 = 0; k0 < K_; k0 += 32) {
        __syncthreads();
        #pragma unroll
        for (int qq = 0; qq < 2; ++qq) {
            const int slot = wv * 128 + qq * 64 + ln;      // 16B slots, 512 total
            const int row  = slot >> 2;
            const int col  = (slot & 3) * 8;
            gload_lds16(A  + (size_t)(r0 + row) * K_ + k0 + col,
                        &As[(size_t)(wv * 128 + qq * 64) * 8]);
            gload_lds16(Bt + (size_t)(c0 + row) * K_ + k0 + col,
                        &Bs[(size_t)(wv * 128 + qq * 64) * 8]);
        }
        __syncthreads();

        short8 af[4], bfr[4];
        const int qk = lq * 8;
        #pragma unroll
        for (int m = 0; m < 4; ++m)
            af[m] = *(const short8*)&As[(wr * 64 + m * 16 + li) * 32 + qk];
        #pragma unroll
        for (int n = 0; n < 4; ++n)
            bfr[n] = *(const short8*)&Bs[(wc * 64 + n * 16 + li) * 32 + qk];
        #pragma unroll
        for (int m = 0; m < 4; ++m)
            #pragma unroll
            for (int n = 0; n < 4; ++n)
                acc[m][n] = __builtin_amdgcn_mfma_f32_16x16x32_bf16(
                    af[m], bfr[n], acc[m][n], 0, 0, 0);
    }

    // C/D layout: col = lane&15, row = (lane>>4)*4 + reg
    if (EPI == 0) {
        #pragma unroll
        for (int n = 0; n < 4; ++n) {
            const int gcol  = c0 + wc * 64 + n * 16 + li;   // 0..3071
            const int which = gcol >> 10;                    // uniform per frag
            const int rem   = gcol & 1023;
            const int h     = rem >> 6;
            const int dh    = rem & 63;
            const float scl = (which == 0) ? 0.125f : 1.0f;
            const float bb  = bias[gcol];
            #pragma unroll
            for (int m = 0; m < 4; ++m)
                #pragma unroll
                for (int r = 0; r < 4; ++r) {
                    const int grow = r0 + wr * 64 + m * 16 + lq * 4 + r;
                    const int b = grow >> 11, s = grow & (S_ - 1);
                    const u16 val = f2bf((acc[m][n][r] + bb) * scl);
                    if (which == 2) {
                        // V transposed: [bh][dh][s]
                        vd[((size_t)(b * H_ + h) * DH_ + dh) * S_ + s] = val;
                    } else {
                        u16* dst = (which == 0) ? qd : kd;
                        dst[((size_t)(b * H_ + h) * S_ + s) * DH_ + dh] = val;
                    }
                }
        }
    } else {
        #pragma unroll
        for (int n = 0; n < 4; ++n) {
            const int gcol = c0 + wc * 64 + n * 16 + li;
            const float bb = bias[gcol];
            #pragma unroll
            for (int m = 0; m < 4; ++m)
                #pragma unroll
                for (int r = 0; r < 4; ++r) {
                    const int grow = r0 + wr * 64 + m * 16 + lq * 4 + r;
                    outp[(size_t)grow * D_ + gcol] = acc[m][n][r] + bb;
                }
        }
    }
}

// ---------------------------------------------------------------------------
// flash attention v2.  block = 4 waves, one (b,h) x 64-query tile; wave wv
// owns q-rows wv*16..+15.  Q frags direct from global (read once).  K and
// V^T tiles reg-staged into XOR-swizzled LDS (byte ^= (row&7)<<4) -> all
// b128 reads & writes land 2 lanes/bank (free).  P round-trip swizzled too.
// LDS 24KB -> 4 blocks/CU at grid 1024.
// ---------------------------------------------------------------------------
__global__ __launch_bounds__(256, 4) void attn_mfma(
    const u16* __restrict__ qws, const u16* __restrict__ kws,
    const u16* __restrict__ vtws, u16* __restrict__ ao)
{
    __shared__ u16 Ks[64 * 64];   // [kv][d]  swizzled, 128B rows
    __shared__ u16 Vt[64 * 64];   // [d][kv]  swizzled
    __shared__ u16 Ps[64 * 64];   // [qrow][kv] swizzled, wave-private strips

    const int t  = threadIdx.x;
    const int wv = t >> 6, ln = t & 63;
    const int li = ln & 15, lq = ln >> 4;
    const int bh = blockIdx.y;
    const int q0 = blockIdx.x * 64;

    const u16* Kp  = kws  + (size_t)bh * S_ * DH_;
    const u16* Vtp = vtws + (size_t)bh * DH_ * S_;

    // Q fragments: lane (li,lq) needs Q[q0+wv*16+li][ks*32+lq*8 .. +8]
    short8 aq[2];
    {
        const u16* Qp = qws + ((size_t)bh * S_ + q0 + wv * 16 + li) * DH_ + lq * 8;
        aq[0] = *(const short8*)(Qp);
        aq[1] = *(const short8*)(Qp + 32);
    }

    f32x4 o[4];
    #pragma unroll
    for (int n = 0; n < 4; ++n) o[n] = (f32x4){0.f, 0.f, 0.f, 0.f};
    float mrow[4] = {-3e38f, -3e38f, -3e38f, -3e38f};
    float lrow[4] = {0.f, 0.f, 0.f, 0.f};

    // staging geometry: 512 chunks of 16B per 8KB tile; this thread's chunk
    // row = chunk>>3 (128B rows), col16 = chunk&7; swizzle ^= (row&7)<<4
    for (int kt = 0; kt < S_ / 64; ++kt) {
        const int k0 = kt * 64;
        __syncthreads();                     // prior tile's frag reads done
        #pragma unroll
        for (int i = 0; i < 2; ++i) {
            const int s   = t + i * 256;
            const int row = s >> 3;
            const int c16 = s & 7;
            const int off = (row * 128 + c16 * 16) ^ ((row & 7) << 4);
            // K: global [kv][d]
            *(short8*)((char*)Ks + off) =
                *(const short8*)(Kp + (size_t)(k0 + row) * DH_ + c16 * 8);
            // V^T: global [d][S]
            *(short8*)((char*)Vt + off) =
                *(const short8*)(Vtp + (size_t)row * S_ + k0 + c16 * 8);
        }
        __syncthreads();

        // S = Q K^T  (strip: 16 q-rows x 64 kv)
        f32x4 sacc[4];
        #pragma unroll
        for (int j = 0; j < 4; ++j) sacc[j] = (f32x4){0.f, 0.f, 0.f, 0.f};
        __builtin_amdgcn_s_setprio(1);
        #pragma unroll
        for (int ks = 0; ks < 2; ++ks) {
            #pragma unroll
            for (int j = 0; j < 4; ++j) {
                const int rrow = j * 16 + li;
                const int roff = (rrow * 128 + ks * 64 + lq * 16) ^ ((li & 7) << 4);
                short8 bk = *(const short8*)((char*)Ks + roff);
                sacc[j] = __builtin_amdgcn_mfma_f32_16x16x32_bf16(aq[ks], bk, sacc[j], 0, 0, 0);
            }
        }
        __builtin_amdgcn_s_setprio(0);

        // online softmax; rows lq*4+r of strip, cols j*16+li
        #pragma unroll
        for (int r = 0; r < 4; ++r) {
            float mx = fmaxf(fmaxf(sacc[0][r], sacc[1][r]), fmaxf(sacc[2][r], sacc[3][r]));
            mx = fmaxf(mx, __shfl_xor(mx, 1));
            mx = fmaxf(mx, __shfl_xor(mx, 2));
            mx = fmaxf(mx, __shfl_xor(mx, 4));
            mx = fmaxf(mx, __shfl_xor(mx, 8));
            const float mnew = fmaxf(mrow[r], mx);
            const float p0 = __expf(sacc[0][r] - mnew);
            const float p1 = __expf(sacc[1][r] - mnew);
            const float p2 = __expf(sacc[2][r] - mnew);
            const float p3 = __expf(sacc[3][r] - mnew);
            float rs = p0 + p1 + p2 + p3;
            rs += __shfl_xor(rs, 1);
            rs += __shfl_xor(rs, 2);
            rs += __shfl_xor(rs, 4);
            rs += __shfl_xor(rs, 8);
            const float scl = __expf(mrow[r] - mnew);
            lrow[r] = lrow[r] * scl + rs;
            mrow[r] = mnew;
            const int prow = wv * 16 + lq * 4 + r;
            const int pbase = prow * 128;
            const int psw   = (prow & 7) << 4;
            *(u16*)((char*)Ps + ((pbase + (     li) * 2) ^ psw)) = f2bf(p0);
            *(u16*)((char*)Ps + ((pbase + (16 + li) * 2) ^ psw)) = f2bf(p1);
            *(u16*)((char*)Ps + ((pbase + (32 + li) * 2) ^ psw)) = f2bf(p2);
            *(u16*)((char*)Ps + ((pbase + (48 + li) * 2) ^ psw)) = f2bf(p3);
            #pragma unroll
            for (int n = 0; n < 4; ++n) o[n][r] *= scl;
        }

        // O += P V  (P strip wave-private; Vt read as B-operand [kv][d-col])
        __builtin_amdgcn_s_setprio(1);
        #pragma unroll
        for (int ks = 0; ks < 2; ++ks) {
            const int arow = wv * 16 + li;
            const int aoff = (arow * 128 + ks * 64 + lq * 16) ^ ((li & 7) << 4);
            short8 ap = *(const short8*)((char*)Ps + aoff);
            #pragma unroll
            for (int n = 0; n < 4; ++n) {
                const int vrow = n * 16 + li;
                const int voff = (vrow * 128 + ks * 64 + lq * 16) ^ ((li & 7) << 4);
                short8 bv = *(const short8*)((char*)Vt + voff);
                o[n] = __builtin_amdgcn_mfma_f32_16x16x32_bf16(ap, bv, o[n], 0, 0, 0);
            }
        }
        __builtin_amdgcn_s_setprio(0);
    }

    // normalize + write merged-head bf16 [B*S][D]
    const int b = bh >> 4, h = bh & 15;
    #pragma unroll
    for (int r = 0; r < 4; ++r) {
        const float inv = 1.0f / lrow[r];
        const int s = q0 + wv * 16 + lq * 4 + r;
        #pragma unroll
        for (int n = 0; n < 4; ++n) {
            const int col = h * 64 + n * 16 + li;
            ao[((size_t)b * S_ + s) * D_ + col] = f2bf(o[n][r] * inv);
        }
    }
}

// ---------------------------------------------------------------------------
extern "C" void kernel_launch(void* const* d_in, const int* in_sizes, int n_in,
                              void* d_out, int out_size, void* d_ws, size_t ws_size,
                              hipStream_t stream)
{
    const float* x      = (const float*)d_in[0];
    const float* w_attn = (const float*)d_in[1];
    const float* b_attn = (const float*)d_in[2];
    const float* w_proj = (const float*)d_in[3];
    const float* b_proj = (const float*)d_in[4];
    float* out = (float*)d_out;

    char* ws = (char*)d_ws;
    u16* x_bf = (u16*)(ws);                              //  8 MB  [4096][1024]
    u16* wat  = (u16*)(ws + 8388608);                    //  6 MB  [3072][1024] (W_attn^T)
    u16* wpj  = (u16*)(ws + 14680064);                   //  2 MB  [1024][1024] (W_proj^T)
    u16* qws  = (u16*)(ws + 16777216);                   //  8 MB  [32][2048][64] (pre-scaled)
    u16* kws  = (u16*)(ws + 25165824);                   //  8 MB  [32][2048][64]
    u16* vtws = (u16*)(ws + 33554432);                   //  8 MB  [32][64][2048]  V^T
    u16* ao   = (u16*)(ws + 41943040);                   //  8 MB  [4096][1024]
    // total 48 MB

    convert_f32_bf16<<<1024, 256, 0, stream>>>(x, x_bf, M_ * K_ / 4);
    transpose_f32_bf16<<<dim3(N3_ / 32, K_ / 32), 256, 0, stream>>>(w_attn, wat, K_, N3_);
    transpose_f32_bf16<<<dim3(D_ / 32, K_ / 32), 256, 0, stream>>>(w_proj, wpj, K_, D_);

    mfma_gemm<0><<<dim3(N3_ / 128, M_ / 128), 256, 0, stream>>>(
        x_bf, wat, b_attn, qws, kws, vtws, nullptr);

    attn_mfma<<<dim3(S_ / 64, 32), 256, 0, stream>>>(qws, kws, vtws, ao);

    mfma_gemm<1><<<dim3(D_ / 128, M_ / 128), 256, 0, stream>>>(
        ao, wpj, b_proj, nullptr, nullptr, nullptr, out);
}